// Round 1
// baseline (1584.115 us; speedup 1.0000x reference)
//
#include <hip/hip_runtime.h>

#define NN 262144
#define KK 1024
#define DD 64
#define DECAY 0.99f
#define ONE_MINUS_DECAY 0.01f
#define EPSF 1e-5f
#define COMMIT 0.25f

// --- precompute 0.5*||c||^2 per code ---------------------------------------
__global__ __launch_bounds__(256) void k_csq(const float* __restrict__ cb,
                                             float* __restrict__ csq_half) {
    int k = blockIdx.x * 256 + threadIdx.x;
    const float4* c4 = (const float4*)(cb + (size_t)k * DD);
    float s = 0.f;
#pragma unroll
    for (int j = 0; j < DD / 4; ++j) {
        float4 c = c4[j];
        s += c.x * c.x + c.y * c.y + c.z * c.z + c.w * c.w;
    }
    csq_half[k] = 0.5f * s;
}

// --- assignment: argmin_k (0.5*||c||^2 - x.c), gather quantized, loss, hist -
__global__ __launch_bounds__(256) void k_assign(
    const float* __restrict__ x, const float* __restrict__ cb,
    const float* __restrict__ csq_half,
    float* __restrict__ quant, int* __restrict__ idx_int,
    int* __restrict__ counts, float* __restrict__ loss_acc)
{
    int i = blockIdx.x * 256 + threadIdx.x;
    float4 xr[16];
    const float4* xrow = (const float4*)(x + (size_t)i * DD);
#pragma unroll
    for (int j = 0; j < 16; ++j) xr[j] = xrow[j];

    float best = 3.4e38f;
    int bestk = 0;
    for (int k = 0; k < KK; ++k) {
        // k is wave-uniform -> these loads should become s_load; FMAs get an
        // SGPR src operand, keeping VMEM off the critical path.
        const float4* c4 = (const float4*)(cb + k * DD);
        float a0 = 0.f, a1 = 0.f, a2 = 0.f, a3 = 0.f;
#pragma unroll
        for (int j = 0; j < 16; ++j) {
            float4 c = c4[j];
            a0 += xr[j].x * c.x;
            a1 += xr[j].y * c.y;
            a2 += xr[j].z * c.z;
            a3 += xr[j].w * c.w;
        }
        float dot = (a0 + a1) + (a2 + a3);
        float dp = csq_half[k] - dot;   // argmin proxy (xsq constant per row)
        bool better = dp < best;        // strict < keeps first min (jnp.argmin)
        best  = better ? dp : best;
        bestk = better ? k : bestk;
    }

    idx_int[i] = bestk;
    atomicAdd(&counts[bestk], 1);

    // gather quantized row (codebook is L2-resident) + per-thread sq error
    const float4* q4 = (const float4*)(cb + (size_t)bestk * DD);
    float4* o4 = (float4*)(quant + (size_t)i * DD);
    float err = 0.f;
#pragma unroll
    for (int j = 0; j < 16; ++j) {
        float4 q = q4[j];
        o4[j] = q;
        float ex = q.x - xr[j].x, ey = q.y - xr[j].y;
        float ez = q.z - xr[j].z, ew = q.w - xr[j].w;
        err += ex * ex + ey * ey + ez * ez + ew * ew;
    }
#pragma unroll
    for (int off = 32; off > 0; off >>= 1) err += __shfl_down(err, off);
    if ((threadIdx.x & 63) == 0) atomicAdd(loss_acc, err);
}

// --- single block: EMA cluster size, n-reduce, smoothed, prefix-scan, loss --
__global__ __launch_bounds__(1024) void k_mid(
    const int* __restrict__ counts, const float* __restrict__ ema_cs,
    const float* __restrict__ loss_acc,
    float* __restrict__ new_cs, float* __restrict__ loss_out,
    float* __restrict__ smoothed_inv, int* __restrict__ offsets,
    int* __restrict__ cursor)
{
    int t = threadIdx.x;
    int cnt = counts[t];
    float ncs = DECAY * ema_cs[t] + ONE_MINUS_DECAY * (float)cnt;

    // n = sum(new_cluster_size)
    float s = ncs;
#pragma unroll
    for (int off = 32; off > 0; off >>= 1) s += __shfl_down(s, off);
    __shared__ float wsum[16];
    __shared__ float ntot_s;
    if ((t & 63) == 0) wsum[t >> 6] = s;
    __syncthreads();
    if (t == 0) {
        float tt = 0.f;
        for (int w = 0; w < 16; ++w) tt += wsum[w];
        ntot_s = tt;
    }
    __syncthreads();
    float n = ntot_s;

    float sm = (ncs + EPSF) / (n + (float)KK * EPSF) * n;
    new_cs[t] = ncs;
    smoothed_inv[t] = 1.0f / sm;

    // exclusive scan of counts (Hillis-Steele)
    __shared__ int sc[1024];
    sc[t] = cnt;
    __syncthreads();
    for (int off = 1; off < 1024; off <<= 1) {
        int v = (t >= off) ? sc[t - off] : 0;
        __syncthreads();
        sc[t] += v;
        __syncthreads();
    }
    int excl = sc[t] - cnt;
    offsets[t] = excl;
    cursor[t] = excl;

    if (t == 0) loss_out[0] = COMMIT * loss_acc[0] / (float)(NN * DD);
}

// --- scatter rows into per-code segments; convert idx slot to float in place -
__global__ __launch_bounds__(256) void k_scatter(
    int* __restrict__ idx_inout, int* __restrict__ cursor,
    int* __restrict__ perm)
{
    int i = blockIdx.x * 256 + threadIdx.x;
    int k = idx_inout[i];
    int pos = atomicAdd(&cursor[k], 1);
    perm[pos] = i;
    ((float*)idx_inout)[i] = (float)k;   // own-element read happened above
}

// --- per-code segment reduce: dw, new_ema_w, new_codebook -------------------
__global__ __launch_bounds__(256) void k_reduce(
    const float* __restrict__ x, const int* __restrict__ perm,
    const int* __restrict__ offsets, const int* __restrict__ counts,
    const float* __restrict__ ema_w, const float* __restrict__ smoothed_inv,
    float* __restrict__ new_ema_w, float* __restrict__ new_cb)
{
    int k = blockIdx.x;
    int d = threadIdx.x & 63;
    int rg = threadIdx.x >> 6;
    int start = offsets[k], cnt = counts[k];
    float s = 0.f;
    for (int r = rg; r < cnt; r += 4) {
        int row = perm[start + r];
        s += x[(size_t)row * DD + d];     // 256B coalesced per row
    }
    __shared__ float red[256];
    red[threadIdx.x] = s;
    __syncthreads();
    if (rg == 0) {
        float dw = red[d] + red[64 + d] + red[128 + d] + red[192 + d];
        float nw = DECAY * ema_w[k * DD + d] + ONE_MINUS_DECAY * dw;
        new_ema_w[k * DD + d] = nw;
        new_cb[k * DD + d] = nw * smoothed_inv[k];
    }
}

extern "C" void kernel_launch(void* const* d_in, const int* in_sizes, int n_in,
                              void* d_out, int out_size, void* d_ws, size_t ws_size,
                              hipStream_t stream)
{
    const float* x      = (const float*)d_in[0];
    const float* cb     = (const float*)d_in[1];
    const float* ema_cs = (const float*)d_in[2];
    const float* ema_w  = (const float*)d_in[3];

    float* out      = (float*)d_out;
    float* quant    = out;                                   // [N*D]
    float* loss_out = out + (size_t)NN * DD;                 // [1]
    int*   idx_reg  = (int*)(out + (size_t)NN * DD + 1);     // [N] (float slot)
    float* new_cb   = out + (size_t)NN * DD + 1 + NN;        // [K*D]
    float* new_cs   = new_cb + (size_t)KK * DD;              // [K]
    float* new_emaw = new_cs + KK;                           // [K*D]

    char* ws = (char*)d_ws;
    float* loss_acc     = (float*)(ws + 0);
    int*   counts       = (int*)(ws + 256);
    int*   offsets      = (int*)(ws + 256 + 4096);
    int*   cursor       = (int*)(ws + 256 + 8192);
    float* csq_half     = (float*)(ws + 256 + 12288);
    float* smoothed_inv = (float*)(ws + 256 + 16384);
    int*   perm         = (int*)(ws + 256 + 20480);

    hipMemsetAsync(d_ws, 0, 256 + 4096, stream);  // loss_acc + counts

    k_csq    <<<KK / 256, 256, 0, stream>>>(cb, csq_half);
    k_assign <<<NN / 256, 256, 0, stream>>>(x, cb, csq_half, quant, idx_reg,
                                            counts, loss_acc);
    k_mid    <<<1, 1024, 0, stream>>>(counts, ema_cs, loss_acc, new_cs,
                                      loss_out, smoothed_inv, offsets, cursor);
    k_scatter<<<NN / 256, 256, 0, stream>>>(idx_reg, cursor, perm);
    k_reduce <<<KK, 256, 0, stream>>>(x, perm, offsets, counts, ema_w,
                                      smoothed_inv, new_emaw, new_cb);
}

// Round 2
// 1178.434 us; speedup vs baseline: 1.3443x; 1.3443x over previous
//
#include <hip/hip_runtime.h>

#define NN 262144
#define KK 1024
#define DD 64
#define DECAY 0.99f
#define ONE_MINUS_DECAY 0.01f
#define EPSF 1e-5f
#define COMMIT 0.25f

// --- precompute 0.5*||c||^2 per code ---------------------------------------
__global__ __launch_bounds__(256) void k_csq(const float* __restrict__ cb,
                                             float* __restrict__ csq_half) {
    int k = blockIdx.x * 256 + threadIdx.x;
    const float4* c4 = (const float4*)(cb + (size_t)k * DD);
    float s = 0.f;
#pragma unroll
    for (int j = 0; j < DD / 4; ++j) {
        float4 c = c4[j];
        s += c.x * c.x + c.y * c.y + c.z * c.z + c.w * c.w;
    }
    csq_half[k] = 0.5f * s;
}

// --- assignment: argmin_k (0.5*||c||^2 - x.c), gather quantized, loss, hist -
// __launch_bounds__(256,4): 4 waves/EU -> VGPR cap 128. The x-row (64 VGPRs)
// must stay register-resident; round-1's bare (256) capped VGPRs at 64 and
// spilled it (VGPR_Count=64, FMA-efficiency ~35% of VALUBusy).
__global__ __launch_bounds__(256, 4) void k_assign(
    const float* __restrict__ x, const float* __restrict__ cb,
    const float* __restrict__ csq_half,
    float* __restrict__ quant, int* __restrict__ idx_int,
    int* __restrict__ counts, float* __restrict__ loss_acc)
{
    int i = blockIdx.x * 256 + threadIdx.x;
    float4 xr[16];
    const float4* xrow = (const float4*)(x + (size_t)i * DD);
#pragma unroll
    for (int j = 0; j < 16; ++j) xr[j] = xrow[j];

    float best = 3.4e38f;
    int bestk = 0;
    for (int k = 0; k < KK; ++k) {
        // k is wave-uniform -> codebook row comes in via s_load on the SMEM
        // pipe; FMAs take the SGPR as one source operand.
        const float4* c4 = (const float4*)(cb + k * DD);
        float a0 = 0.f, a1 = 0.f, a2 = 0.f, a3 = 0.f;
#pragma unroll
        for (int j = 0; j < 16; ++j) {
            float4 c = c4[j];
            a0 += xr[j].x * c.x;
            a1 += xr[j].y * c.y;
            a2 += xr[j].z * c.z;
            a3 += xr[j].w * c.w;
        }
        float dot = (a0 + a1) + (a2 + a3);
        float dp = csq_half[k] - dot;   // argmin proxy (xsq constant per row)
        bool better = dp < best;        // strict < keeps first min (jnp.argmin)
        best  = better ? dp : best;
        bestk = better ? k : bestk;
    }

    idx_int[i] = bestk;
    atomicAdd(&counts[bestk], 1);

    // gather quantized row (codebook is L1/L2-resident) + per-thread sq error
    const float4* q4 = (const float4*)(cb + (size_t)bestk * DD);
    float4* o4 = (float4*)(quant + (size_t)i * DD);
    float err = 0.f;
#pragma unroll
    for (int j = 0; j < 16; ++j) {
        float4 q = q4[j];
        o4[j] = q;
        float ex = q.x - xr[j].x, ey = q.y - xr[j].y;
        float ez = q.z - xr[j].z, ew = q.w - xr[j].w;
        err += ex * ex + ey * ey + ez * ez + ew * ew;
    }
#pragma unroll
    for (int off = 32; off > 0; off >>= 1) err += __shfl_down(err, off);
    if ((threadIdx.x & 63) == 0) atomicAdd(loss_acc, err);
}

// --- single block: EMA cluster size, n-reduce, smoothed, prefix-scan, loss --
__global__ __launch_bounds__(1024) void k_mid(
    const int* __restrict__ counts, const float* __restrict__ ema_cs,
    const float* __restrict__ loss_acc,
    float* __restrict__ new_cs, float* __restrict__ loss_out,
    float* __restrict__ smoothed_inv, int* __restrict__ offsets,
    int* __restrict__ cursor)
{
    int t = threadIdx.x;
    int cnt = counts[t];
    float ncs = DECAY * ema_cs[t] + ONE_MINUS_DECAY * (float)cnt;

    // n = sum(new_cluster_size)
    float s = ncs;
#pragma unroll
    for (int off = 32; off > 0; off >>= 1) s += __shfl_down(s, off);
    __shared__ float wsum[16];
    __shared__ float ntot_s;
    if ((t & 63) == 0) wsum[t >> 6] = s;
    __syncthreads();
    if (t == 0) {
        float tt = 0.f;
        for (int w = 0; w < 16; ++w) tt += wsum[w];
        ntot_s = tt;
    }
    __syncthreads();
    float n = ntot_s;

    float sm = (ncs + EPSF) / (n + (float)KK * EPSF) * n;
    new_cs[t] = ncs;
    smoothed_inv[t] = 1.0f / sm;

    // exclusive scan of counts (Hillis-Steele)
    __shared__ int sc[1024];
    sc[t] = cnt;
    __syncthreads();
    for (int off = 1; off < 1024; off <<= 1) {
        int v = (t >= off) ? sc[t - off] : 0;
        __syncthreads();
        sc[t] += v;
        __syncthreads();
    }
    int excl = sc[t] - cnt;
    offsets[t] = excl;
    cursor[t] = excl;

    if (t == 0) loss_out[0] = COMMIT * loss_acc[0] / (float)(NN * DD);
}

// --- scatter rows into per-code segments; record code per position ---------
__global__ __launch_bounds__(256) void k_scatter(
    int* __restrict__ idx_inout, int* __restrict__ cursor,
    int* __restrict__ perm, int* __restrict__ pcode)
{
    int i = blockIdx.x * 256 + threadIdx.x;
    int k = idx_inout[i];
    int pos = atomicAdd(&cursor[k], 1);
    perm[pos] = i;
    pcode[pos] = k;
    ((float*)idx_inout)[i] = (float)k;   // own-element read happened above
}

// --- balanced segment sum: equal 64-row windows of sorted rows, run-flush ---
// Replaces one-block-per-code reduce (skewed Voronoi counts -> worst block
// serialized MBs of gathers). Here every wave does exactly 64 row-gathers;
// atomics only at run boundaries (~1.25 per wave).
__global__ __launch_bounds__(256) void k_segsum(
    const float* __restrict__ x, const int* __restrict__ perm,
    const int* __restrict__ pcode, float* __restrict__ dw)
{
    int w = blockIdx.x * 4 + (threadIdx.x >> 6);  // wave id, 4096 total
    int lane = threadIdx.x & 63;
    int base = w * 64;
    float acc = 0.f;
    int cur = pcode[base];                         // wave-uniform
    for (int r = 0; r < 64; ++r) {
        int c = pcode[base + r];
        if (c != cur) {                            // wave-uniform branch
            atomicAdd(&dw[cur * DD + lane], acc);
            acc = 0.f; cur = c;
        }
        int row = perm[base + r];
        acc += x[(size_t)row * DD + lane];         // 256B coalesced gather
    }
    atomicAdd(&dw[cur * DD + lane], acc);
}

// --- EMA weight update + codebook normalize --------------------------------
__global__ __launch_bounds__(256) void k_final(
    const float* __restrict__ dw, const float* __restrict__ ema_w,
    const float* __restrict__ smoothed_inv,
    float* __restrict__ new_ema_w, float* __restrict__ new_cb)
{
    int i = blockIdx.x * 256 + threadIdx.x;        // K*D = 65536
    int k = i >> 6;
    float nw = DECAY * ema_w[i] + ONE_MINUS_DECAY * dw[i];
    new_ema_w[i] = nw;
    new_cb[i] = nw * smoothed_inv[k];
}

extern "C" void kernel_launch(void* const* d_in, const int* in_sizes, int n_in,
                              void* d_out, int out_size, void* d_ws, size_t ws_size,
                              hipStream_t stream)
{
    const float* x      = (const float*)d_in[0];
    const float* cb     = (const float*)d_in[1];
    const float* ema_cs = (const float*)d_in[2];
    const float* ema_w  = (const float*)d_in[3];

    float* out      = (float*)d_out;
    float* quant    = out;                                   // [N*D]
    float* loss_out = out + (size_t)NN * DD;                 // [1]
    int*   idx_reg  = (int*)(out + (size_t)NN * DD + 1);     // [N] (float slot)
    float* new_cb   = out + (size_t)NN * DD + 1 + NN;        // [K*D]
    float* new_cs   = new_cb + (size_t)KK * DD;              // [K]
    float* new_emaw = new_cs + KK;                           // [K*D]

    char* ws = (char*)d_ws;
    // [loss_acc 256 | counts 4096 | dw 262144]  <- one contiguous memset
    float* loss_acc     = (float*)(ws + 0);
    int*   counts       = (int*)(ws + 256);
    float* dw           = (float*)(ws + 256 + 4096);
    char*  ws2          = ws + 256 + 4096 + 262144;
    int*   offsets      = (int*)(ws2 + 0);
    int*   cursor       = (int*)(ws2 + 4096);
    float* csq_half     = (float*)(ws2 + 8192);
    float* smoothed_inv = (float*)(ws2 + 12288);
    int*   perm         = (int*)(ws2 + 16384);
    int*   pcode        = (int*)(ws2 + 16384 + (size_t)NN * 4);

    hipMemsetAsync(d_ws, 0, 256 + 4096 + 262144, stream);

    k_csq    <<<KK / 256, 256, 0, stream>>>(cb, csq_half);
    k_assign <<<NN / 256, 256, 0, stream>>>(x, cb, csq_half, quant, idx_reg,
                                            counts, loss_acc);
    k_mid    <<<1, 1024, 0, stream>>>(counts, ema_cs, loss_acc, new_cs,
                                      loss_out, smoothed_inv, offsets, cursor);
    k_scatter<<<NN / 256, 256, 0, stream>>>(idx_reg, cursor, perm, pcode);
    k_segsum <<<NN / (256 * 64) , 256, 0, stream>>>(x, perm, pcode, dw);
    k_final  <<<KK * DD / 256, 256, 0, stream>>>(dw, ema_w, smoothed_inv,
                                                 new_emaw, new_cb);
}